// Round 11
// baseline (412.864 us; speedup 1.0000x reference)
//
#include <hip/hip_runtime.h>
#include <hip/hip_bf16.h>

#define NN 10000
#define NE 100000

typedef __bf16 bf16x8 __attribute__((ext_vector_type(8)));
typedef float  f32x4  __attribute__((ext_vector_type(4)));

__device__ __forceinline__ f32x4 relu4(f32x4 a) {
    a.x = fmaxf(a.x, 0.f); a.y = fmaxf(a.y, 0.f);
    a.z = fmaxf(a.z, 0.f); a.w = fmaxf(a.w, 0.f);
    return a;
}

// ---------------- one-time kernels ----------------

__global__ void k_deg(const int* __restrict__ eidx, int* __restrict__ deg) {
    int e = blockIdx.x * blockDim.x + threadIdx.x;
    if (e < NE) atomicAdd(&deg[eidx[e]], 1);
}

__global__ void k_scan(const int* __restrict__ deg, int* __restrict__ rowptr,
                       int* __restrict__ cursor) {
    __shared__ int ssum[256];
    const int tid = threadIdx.x;
    const int CH = 40;
    const int base = tid * CH;
    int s = 0;
    for (int i = 0; i < CH; ++i) { int n = base + i; if (n < NN) s += deg[n]; }
    ssum[tid] = s;
    __syncthreads();
    for (int off = 1; off < 256; off <<= 1) {
        int t = (tid >= off) ? ssum[tid - off] : 0;
        __syncthreads();
        ssum[tid] += t;
        __syncthreads();
    }
    int run = ssum[tid] - s;
    for (int i = 0; i < CH; ++i) {
        int n = base + i;
        if (n < NN) { rowptr[n] = run; cursor[n] = run; run += deg[n]; }
    }
    if (tid == 255) rowptr[NN] = ssum[255];
}

__global__ void k_fill(const int* __restrict__ eidx, int* __restrict__ cursor,
                       int* __restrict__ ebyrow) {
    int e = blockIdx.x * blockDim.x + threadIdx.x;
    if (e < NE) {
        int r = eidx[e];
        int slot = atomicAdd(&cursor[r], 1);
        ebyrow[slot] = e;
    }
}

__global__ void k_init(const float* __restrict__ x, const float* __restrict__ fc1w,
                       const float* __restrict__ fc1b, const float* __restrict__ cinit,
                       const int* __restrict__ deg,
                       float* __restrict__ h, float* __restrict__ coord,
                       float* __restrict__ deg_inv) {
    int n = blockIdx.x * blockDim.x + threadIdx.x;
    if (n >= NN) return;
    float x0 = x[n*3+0], x1 = x[n*3+1], x2 = x[n*3+2];
    #pragma unroll
    for (int j = 0; j < 32; j += 4) {
        f32x4 a = *(const f32x4*)(fc1b + j);
        a += x0 * (*(const f32x4*)(fc1w + 0*32 + j));
        a += x1 * (*(const f32x4*)(fc1w + 1*32 + j));
        a += x2 * (*(const f32x4*)(fc1w + 2*32 + j));
        *(f32x4*)(h + n*32 + j) = a;   // no relu on fc1 (matches reference)
    }
    coord[n*3+0] = cinit[n*3+0];
    coord[n*3+1] = cinit[n*3+1];
    coord[n*3+2] = cinit[n*3+2];
    int d = deg[n];
    deg_inv[n] = 1.0f / (float)(d > 1 ? d : 1);
}

// Swizzle ker_w3 [128,1024] and ker_w2 [64,128] fp32 -> bf16 MFMA-B fragment order.
__global__ void k_wsw(const float* __restrict__ w3, __bf16* __restrict__ w3sw,
                      const float* __restrict__ w2, __bf16* __restrict__ w2sw) {
    int t = blockIdx.x * blockDim.x + threadIdx.x;
    if (t < 131072) {
        int jj = t & 7;
        int L  = (t >> 3) & 63;
        int ks = (t >> 9) & 3;
        int jt = (t >> 11) & 1;
        int i  = t >> 12;
        int c    = ks*32 + (L >> 4)*8 + jj;              // K index 0..127
        int colv = i*32 + jt*16 + (L & 15);              // output col 0..1023
        w3sw[t] = (__bf16)w3[c*1024 + colv];
    } else if (t < 131072 + 8192) {
        int u = t - 131072;
        int jj = u & 7;
        int L  = (u >> 3) & 63;
        int ks = (u >> 9) & 1;
        int nt = u >> 10;
        int c1 = ks*32 + (L >> 4)*8 + jj;
        int c2 = nt*16 + (L & 15);
        w2sw[u] = (__bf16)w2[c1*128 + c2];
    }
}

// ---------------- the fused per-layer kernel ----------------
// One block = 64 edges, 256 threads (4 waves).
// Phase 1: edge geometry + kernel-MLP layer1; 4 threads/edge via wave-split
//          channels (wave w computes ch [16w,16w+16)) -> k1 LDS tile (9.2 KB).
// Phase 2: layer2 MFMA, nt-tiles split 2/wave -> k2 LDS tile (16 KB, XOR-swizzled
//          in A-frag chunk layout). Each wave then loads afrag[4][4] (b128).
// Phase 3: round-10 k_gemm i-loop (wave owns 8 of 32 i-blocks, private wk tile
//          OVERLAYING k1+k2), einsum dot, mv exchange, phi on wave 0.
// LDS total: max(k1 9.2 + k2 16, wk 36.9) = 36.9 KB -> 4 blocks/CU.
__global__ __launch_bounds__(256, 2)
void k_layer(const float* __restrict__ coord, const int* __restrict__ eidx,
             const float* __restrict__ eattr,
             const float* __restrict__ w1, const float* __restrict__ b1,
             const __bf16* __restrict__ w2sw, const float* __restrict__ b2,
             const __bf16* __restrict__ w3sw, const float* __restrict__ b3,
             const float* __restrict__ h,
             const float* __restrict__ cm_w1, const float* __restrict__ cm_b1,
             const float* __restrict__ cm_w2,
             float* __restrict__ cd4, float* __restrict__ m_t,
             float* __restrict__ phiv) {
    __shared__ float smem[4 * 64 * 36];            // 36.9 KB
    __bf16* kt1 = (__bf16*)smem;                   // [0, 9216) B : 64 x 72 bf16
    __bf16* kt2 = (__bf16*)smem + 4608;            // [9216, 25600) B : 64 x 128 bf16
    const int lane = threadIdx.x & 63;
    const int wave = threadIdx.x >> 6;
    const int q = lane >> 4, t = lane & 15;
    const int base = blockIdx.x * 64;

    // ---- phase 1: layer1, wave-split channels (each wave: 16 ch of 64 edges) ----
    const int eg = base + lane;
    const int egc = eg < NE ? eg : NE - 1;
    {
        int r = eidx[egc], c = eidx[NE + egc];
        float dx = coord[r*3+0] - coord[c*3+0];
        float dy = coord[r*3+1] - coord[c*3+1];
        float dz = coord[r*3+2] - coord[c*3+2];
        float rad = dx*dx + dy*dy + dz*dz;
        if (wave == 0 && eg < NE) {
            f32x4 cdv = {dx, dy, dz, rad};
            *(f32x4*)(cd4 + (size_t)eg*4) = cdv;
        }
        float kin[7];
        #pragma unroll
        for (int a = 0; a < 6; ++a) kin[a] = eattr[(size_t)egc*6 + a];
        kin[6] = rad;

        const int g0 = wave * 16;                  // channel group
        f32x4 acc1[4];
        #pragma unroll
        for (int g = 0; g < 4; ++g) acc1[g] = *(const f32x4*)(b1 + g0 + g*4);
        #pragma unroll
        for (int t7 = 0; t7 < 7; ++t7) {
            float kv = kin[t7];
            #pragma unroll
            for (int g = 0; g < 4; ++g)
                acc1[g] += kv * (*(const f32x4*)(w1 + t7*64 + g0 + g*4));
        }
        #pragma unroll
        for (int cc = 0; cc < 2; ++cc) {
            f32x4 a0 = relu4(acc1[cc*2]), a1 = relu4(acc1[cc*2+1]);
            bf16x8 pk = {(__bf16)a0.x, (__bf16)a0.y, (__bf16)a0.z, (__bf16)a0.w,
                         (__bf16)a1.x, (__bf16)a1.y, (__bf16)a1.z, (__bf16)a1.w};
            int chunk = wave*2 + cc;               // 8-ch chunk id 0..7
            *(bf16x8*)(kt1 + lane*72 + ((chunk ^ (lane & 7)) * 8)) = pk;
        }
    }
    __syncthreads();                               // k1 complete

    // ---- phase 2: layer2 MFMA (wave handles nt = 2*wave, 2*wave+1) ----
    {
        bf16x8 af[4][2];
        #pragma unroll
        for (int mt = 0; mt < 4; ++mt) {
            int ep = mt*16 + t;
            #pragma unroll
            for (int ks = 0; ks < 2; ++ks)
                af[mt][ks] = *(const bf16x8*)(kt1 + ep*72 + (((ks*4 + q) ^ (ep & 7)) * 8));
        }
        #pragma unroll
        for (int nn = 0; nn < 2; ++nn) {
            int nt = wave*2 + nn;
            f32x4 a2[4];
            #pragma unroll
            for (int mt = 0; mt < 4; ++mt) a2[mt] = (f32x4){0.f, 0.f, 0.f, 0.f};
            #pragma unroll
            for (int ks = 0; ks < 2; ++ks) {
                bf16x8 bf_ = *(const bf16x8*)(w2sw + ((nt*2 + ks)*64 + lane) * 8);
                #pragma unroll
                for (int mt = 0; mt < 4; ++mt)
                    a2[mt] = __builtin_amdgcn_mfma_f32_16x16x32_bf16(af[mt][ks], bf_, a2[mt], 0, 0, 0);
            }
            float bias = b2[nt*16 + t];
            int chunk = nt*2 + (t >> 3);           // 8-ch chunk id 0..15
            int tin = t & 7;
            #pragma unroll
            for (int mt = 0; mt < 4; ++mt) {
                #pragma unroll
                for (int rr = 0; rr < 4; ++rr) {
                    int row = mt*16 + q*4 + rr;
                    kt2[row*128 + ((chunk ^ (row & 15)) * 8) + tin] =
                        (__bf16)fmaxf(a2[mt][rr] + bias, 0.f);
                }
            }
        }
    }
    __syncthreads();                               // k2 complete

    // gather h[col] for this lane's edge (overlaps LDS phases via scheduler)
    int col = eidx[NE + egc];
    float hcol[32];
    const f32x4* hp = (const f32x4*)(h + (size_t)col * 32);
    #pragma unroll
    for (int v = 0; v < 8; ++v) {
        f32x4 hv = hp[v];
        hcol[v*4+0] = hv.x; hcol[v*4+1] = hv.y; hcol[v*4+2] = hv.z; hcol[v*4+3] = hv.w;
    }

    // ---- main A-frags from k2 tile (lane-consecutive b128, 2-way max) ----
    bf16x8 afrag[4][4];
    #pragma unroll
    for (int mt = 0; mt < 4; ++mt) {
        int ep = mt*16 + t;
        #pragma unroll
        for (int ks = 0; ks < 4; ++ks) {
            int ck = ks*4 + q;                     // K-chunk 0..15
            afrag[mt][ks] = *(const bf16x8*)(kt2 + ep*128 + ((ck ^ (ep & 15)) * 8));
        }
    }
    __syncthreads();                               // afrag loaded; wk may clobber

    // ---- phase 3: big GEMM i-loop (identical to round-10 k_gemm) ----
    float* wkw = smem + wave * (64 * 36);
    const float* wkrow = wkw + lane * 36;
    float mv[8];

    bf16x8 bcur[8];
    {
        const __bf16* wb0 = w3sw + (size_t)(wave * 8) * 4096;
        #pragma unroll
        for (int f = 0; f < 8; ++f)
            bcur[f] = *(const bf16x8*)(wb0 + (f*64 + lane) * 8);
    }

    #pragma unroll
    for (int ii = 0; ii < 8; ++ii) {
        const int i = wave * 8 + ii;
        f32x4 acc[4][2];
        #pragma unroll
        for (int mt = 0; mt < 4; ++mt) {
            acc[mt][0] = (f32x4){0.f, 0.f, 0.f, 0.f};
            acc[mt][1] = (f32x4){0.f, 0.f, 0.f, 0.f};
        }
        #pragma unroll
        for (int jt = 0; jt < 2; ++jt) {
            #pragma unroll
            for (int ks = 0; ks < 4; ++ks) {
                bf16x8 bfrag = bcur[jt*4 + ks];
                #pragma unroll
                for (int mt = 0; mt < 4; ++mt)
                    acc[mt][jt] = __builtin_amdgcn_mfma_f32_16x16x32_bf16(
                        afrag[mt][ks], bfrag, acc[mt][jt], 0, 0, 0);
            }
        }
        if (ii < 7) {
            const __bf16* wbn = w3sw + (size_t)(i + 1) * 4096;
            #pragma unroll
            for (int f = 0; f < 8; ++f)
                bcur[f] = *(const bf16x8*)(wbn + (f*64 + lane) * 8);
        }
        float bias0 = b3[i*32 + t];
        float bias1 = b3[i*32 + 16 + t];
        #pragma unroll
        for (int mt = 0; mt < 4; ++mt) {
            #pragma unroll
            for (int r = 0; r < 4; ++r) {
                int row = mt*16 + q*4 + r;
                wkw[row*36 + t]      = acc[mt][0][r] + bias0;
                wkw[row*36 + 16 + t] = acc[mt][1][r] + bias1;
            }
        }
        float s = 0.f;
        #pragma unroll
        for (int v = 0; v < 8; ++v) {
            f32x4 wv = *(const f32x4*)(wkrow + v*4);
            s += wv.x*hcol[v*4+0] + wv.y*hcol[v*4+1] + wv.z*hcol[v*4+2] + wv.w*hcol[v*4+3];
        }
        mv[ii] = s;
    }

    if (eg < NE) {
        f32x4 v0 = {mv[0], mv[1], mv[2], mv[3]};
        f32x4 v1 = {mv[4], mv[5], mv[6], mv[7]};
        *(f32x4*)(m_t + (size_t)eg*32 + wave*8)     = v0;
        *(f32x4*)(m_t + (size_t)eg*32 + wave*8 + 4) = v1;
    }

    __syncthreads();
    float* mvx = smem;                             // 32 x 65 floats
    #pragma unroll
    for (int ii = 0; ii < 8; ++ii)
        mvx[(wave*8 + ii)*65 + lane] = mv[ii];
    __syncthreads();
    if (wave == 0) {
        float m2[32];
        #pragma unroll
        for (int i = 0; i < 32; ++i) m2[i] = mvx[i*65 + lane];
        float phi = 0.f;
        for (int o = 0; o < 32; o += 4) {
            f32x4 a = *(const f32x4*)(cm_b1 + o);
            #pragma unroll
            for (int i = 0; i < 32; ++i)
                a += m2[i] * (*(const f32x4*)(cm_w1 + i*32 + o));
            a = relu4(a);
            f32x4 w2 = *(const f32x4*)(cm_w2 + o);
            phi += a.x*w2.x + a.y*w2.y + a.z*w2.z + a.w*w2.w;
        }
        if (eg < NE) phiv[eg] = phi;
    }
}

// CSR gather: 8 threads per node.
__global__ __launch_bounds__(256, 4)
void k_gather(const int* __restrict__ rowptr, const int* __restrict__ ebyrow,
              const float* __restrict__ m_t, const float* __restrict__ phiv,
              const float* __restrict__ cd4, const float* __restrict__ deg_inv,
              float* __restrict__ coord, float* __restrict__ h) {
    int tid = blockIdx.x * blockDim.x + threadIdx.x;
    int n = tid >> 3, sub = tid & 7;
    if (n >= NN) return;
    int st = rowptr[n], en = rowptr[n+1];
    f32x4 am = {0.f, 0.f, 0.f, 0.f};
    float cx = 0.f, cy = 0.f, cz = 0.f;
    for (int p = st; p < en; ++p) {
        int e = ebyrow[p];
        am += *(const f32x4*)(m_t + (size_t)e*32 + sub*4);
        if (sub == 0) {
            f32x4 cd = *(const f32x4*)(cd4 + (size_t)e*4);
            float ph = phiv[e];
            cx += cd.x * ph; cy += cd.y * ph; cz += cd.z * ph;
        }
    }
    float di = deg_inv[n];
    f32x4 hv = *(const f32x4*)(h + (size_t)n*32 + sub*4);
    hv = relu4(hv + am * di);
    *(f32x4*)(h + (size_t)n*32 + sub*4) = hv;
    if (sub == 0) {
        coord[n*3+0] += cx * di;
        coord[n*3+1] += cy * di;
        coord[n*3+2] += cz * di;
    }
}

__global__ __launch_bounds__(256, 4)
void k_final(const float* __restrict__ h, const float* __restrict__ coord,
             const float* __restrict__ fw1, const float* __restrict__ fb1,
             const float* __restrict__ fw2, const float* __restrict__ fb2,
             float* __restrict__ out) {
    int n = blockIdx.x * blockDim.x + threadIdx.x;
    if (n >= NN) return;
    float hreg[32];
    #pragma unroll
    for (int i = 0; i < 32; ++i) hreg[i] = h[n*32 + i];
    float ov = fb2[0];
    for (int o = 0; o < 64; o += 4) {
        f32x4 a = *(const f32x4*)(fb1 + o);
        #pragma unroll
        for (int i = 0; i < 32; ++i)
            a += hreg[i] * (*(const f32x4*)(fw1 + i*64 + o));
        a = relu4(a);
        f32x4 w2 = *(const f32x4*)(fw2 + o);
        ov += a.x*w2.x + a.y*w2.y + a.z*w2.z + a.w*w2.w;
    }
    out[n] = ov;
    out[NN + n*3 + 0] = coord[n*3+0];
    out[NN + n*3 + 1] = coord[n*3+1];
    out[NN + n*3 + 2] = coord[n*3+2];
}

// ---------------- launch ----------------

extern "C" void kernel_launch(void* const* d_in, const int* in_sizes, int n_in,
                              void* d_out, int out_size, void* d_ws, size_t ws_size,
                              hipStream_t stream) {
    const float* x      = (const float*)d_in[0];
    const int*   eidx   = (const int*)  d_in[1];
    const float* eattr  = (const float*)d_in[2];
    const float* cinit  = (const float*)d_in[3];
    const float* fc1w   = (const float*)d_in[4];
    const float* fc1b   = (const float*)d_in[5];
    const float* kw1    = (const float*)d_in[6];
    const float* kb1    = (const float*)d_in[7];
    const float* kw2    = (const float*)d_in[8];
    const float* kb2    = (const float*)d_in[9];
    const float* kw3    = (const float*)d_in[10];
    const float* kb3    = (const float*)d_in[11];
    const float* cmw1   = (const float*)d_in[12];
    const float* cmb1   = (const float*)d_in[13];
    const float* cmw2   = (const float*)d_in[14];
    const float* f2w1   = (const float*)d_in[15];
    const float* f2b1   = (const float*)d_in[16];
    const float* f2w2   = (const float*)d_in[17];
    const float* f2b2   = (const float*)d_in[18];
    float* out = (float*)d_out;

    char* p = (char*)d_ws;
    auto carve = [&](size_t bytes) {
        void* r = (void*)p;
        p += (bytes + 255) & ~(size_t)255;
        return r;
    };
    float*  h        = (float*) carve((size_t)NN * 32 * 4);
    float*  coord    = (float*) carve((size_t)NN * 3 * 4);
    int*    deg      = (int*)   carve((size_t)NN * 4);
    float*  deg_inv  = (float*) carve((size_t)NN * 4);
    int*    rowptr   = (int*)   carve((size_t)(NN + 1) * 4);
    int*    cursor   = (int*)   carve((size_t)NN * 4);
    int*    ebyrow   = (int*)   carve((size_t)NE * 4);
    float*  cd4      = (float*) carve((size_t)NE * 4 * 4);
    float*  m_t      = (float*) carve((size_t)NE * 32 * 4);
    float*  phiv     = (float*) carve((size_t)NE * 4);
    __bf16* w3sw     = (__bf16*)carve((size_t)131072 * 2);
    __bf16* w2sw     = (__bf16*)carve((size_t)8192 * 2);

    const int TB = 256;
    dim3 gE((NE + TB - 1) / TB), gN((NN + TB - 1) / TB), b(TB);
    dim3 gG((NE + 63) / 64);                 // 64 edges per block (k_layer, 256 thr)
    dim3 gA((NN*8 + TB - 1) / TB);

    hipMemsetAsync(deg, 0, (size_t)NN * 4, stream);
    k_deg <<<gE, b, 0, stream>>>(eidx, deg);
    k_scan<<<1, b, 0, stream>>>(deg, rowptr, cursor);
    k_fill<<<gE, b, 0, stream>>>(eidx, cursor, ebyrow);
    k_init<<<gN, b, 0, stream>>>(x, fc1w, fc1b, cinit, deg, h, coord, deg_inv);
    k_wsw <<<544, b, 0, stream>>>(kw3, w3sw, kw2, w2sw);

    for (int d = 0; d < 3; ++d) {
        k_layer<<<gG, b, 0, stream>>>(coord, eidx, eattr, kw1, kb1, w2sw, kb2,
                                      w3sw, kb3, h, cmw1, cmb1, cmw2,
                                      cd4, m_t, phiv);
        k_gather<<<gA, b, 0, stream>>>(rowptr, ebyrow, m_t, phiv, cd4, deg_inv, coord, h);
    }
    k_final<<<gN, b, 0, stream>>>(h, coord, f2w1, f2b1, f2w2, f2b2, out);
}

// Round 12
// 398.167 us; speedup vs baseline: 1.0369x; 1.0369x over previous
//
#include <hip/hip_runtime.h>
#include <hip/hip_bf16.h>

#define NN 10000
#define NE 100000

typedef __bf16 bf16x8 __attribute__((ext_vector_type(8)));
typedef float  f32x4  __attribute__((ext_vector_type(4)));

__device__ __forceinline__ f32x4 relu4(f32x4 a) {
    a.x = fmaxf(a.x, 0.f); a.y = fmaxf(a.y, 0.f);
    a.z = fmaxf(a.z, 0.f); a.w = fmaxf(a.w, 0.f);
    return a;
}

// ---------------- one-time kernels ----------------

__global__ void k_deg(const int* __restrict__ eidx, int* __restrict__ deg) {
    int e = blockIdx.x * blockDim.x + threadIdx.x;
    if (e < NE) atomicAdd(&deg[eidx[e]], 1);
}

__global__ void k_scan(const int* __restrict__ deg, int* __restrict__ rowptr,
                       int* __restrict__ cursor) {
    __shared__ int ssum[256];
    const int tid = threadIdx.x;
    const int CH = 40;
    const int base = tid * CH;
    int s = 0;
    for (int i = 0; i < CH; ++i) { int n = base + i; if (n < NN) s += deg[n]; }
    ssum[tid] = s;
    __syncthreads();
    for (int off = 1; off < 256; off <<= 1) {
        int t = (tid >= off) ? ssum[tid - off] : 0;
        __syncthreads();
        ssum[tid] += t;
        __syncthreads();
    }
    int run = ssum[tid] - s;
    for (int i = 0; i < CH; ++i) {
        int n = base + i;
        if (n < NN) { rowptr[n] = run; cursor[n] = run; run += deg[n]; }
    }
    if (tid == 255) rowptr[NN] = ssum[255];
}

// Also emits pos_r[e]: the row-sorted slot of edge e (inverse permutation).
__global__ void k_fill(const int* __restrict__ eidx, int* __restrict__ cursor,
                       int* __restrict__ ebyrow, int* __restrict__ pos_r) {
    int e = blockIdx.x * blockDim.x + threadIdx.x;
    if (e < NE) {
        int r = eidx[e];
        int slot = atomicAdd(&cursor[r], 1);
        ebyrow[slot] = e;
        pos_r[e] = slot;
    }
}

__global__ void k_init(const float* __restrict__ x, const float* __restrict__ fc1w,
                       const float* __restrict__ fc1b, const float* __restrict__ cinit,
                       const int* __restrict__ deg,
                       float* __restrict__ h, float* __restrict__ coord,
                       float* __restrict__ deg_inv) {
    int n = blockIdx.x * blockDim.x + threadIdx.x;
    if (n >= NN) return;
    float x0 = x[n*3+0], x1 = x[n*3+1], x2 = x[n*3+2];
    #pragma unroll
    for (int j = 0; j < 32; j += 4) {
        f32x4 a = *(const f32x4*)(fc1b + j);
        a += x0 * (*(const f32x4*)(fc1w + 0*32 + j));
        a += x1 * (*(const f32x4*)(fc1w + 1*32 + j));
        a += x2 * (*(const f32x4*)(fc1w + 2*32 + j));
        *(f32x4*)(h + n*32 + j) = a;   // no relu on fc1 (matches reference)
    }
    coord[n*3+0] = cinit[n*3+0];
    coord[n*3+1] = cinit[n*3+1];
    coord[n*3+2] = cinit[n*3+2];
    int d = deg[n];
    deg_inv[n] = 1.0f / (float)(d > 1 ? d : 1);
}

// Swizzle ker_w3 [128,1024] and ker_w2 [64,128] fp32 -> bf16 MFMA-B fragment order.
__global__ void k_wsw(const float* __restrict__ w3, __bf16* __restrict__ w3sw,
                      const float* __restrict__ w2, __bf16* __restrict__ w2sw) {
    int t = blockIdx.x * blockDim.x + threadIdx.x;
    if (t < 131072) {
        int jj = t & 7;
        int L  = (t >> 3) & 63;
        int ks = (t >> 9) & 3;
        int jt = (t >> 11) & 1;
        int i  = t >> 12;
        int c    = ks*32 + (L >> 4)*8 + jj;              // K index 0..127
        int colv = i*32 + jt*16 + (L & 15);              // output col 0..1023
        w3sw[t] = (__bf16)w3[c*1024 + colv];
    } else if (t < 131072 + 8192) {
        int u = t - 131072;
        int jj = u & 7;
        int L  = (u >> 3) & 63;
        int ks = (u >> 9) & 1;
        int nt = u >> 10;
        int c1 = ks*32 + (L >> 4)*8 + jj;
        int c2 = nt*16 + (L & 15);
        w2sw[u] = (__bf16)w2[c1*128 + c2];
    }
}

// ---------------- the fused per-layer kernel ----------------
// One block = 64 edges, 256 threads (4 waves). Phase 1: layer1 (wave-split
// channels) -> kt1. Phase 2: layer2 MFMA -> kt2 (ROW STRIDE 136 bf16: 272B =
// 68 words == 4 mod 32 banks -> kills round-11's 750k bank conflicts).
// Phase 3: i-loop GEMM + einsum dot + phi. m/phi/cd stored at ROW-SORTED
// slots (pos_r) so k_gather streams contiguously.
__global__ __launch_bounds__(256, 2)
void k_layer(const float* __restrict__ coord, const int* __restrict__ eidx,
             const float* __restrict__ eattr,
             const float* __restrict__ w1, const float* __restrict__ b1,
             const __bf16* __restrict__ w2sw, const float* __restrict__ b2,
             const __bf16* __restrict__ w3sw, const float* __restrict__ b3,
             const float* __restrict__ h,
             const float* __restrict__ cm_w1, const float* __restrict__ cm_b1,
             const float* __restrict__ cm_w2, const int* __restrict__ pos_r,
             float* __restrict__ cds, float* __restrict__ m_s,
             float* __restrict__ phis) {
    __shared__ float smem[4 * 64 * 36];            // 36.9 KB
    __bf16* kt1 = (__bf16*)smem;                   // [0, 9216) B : 64 x 72 bf16
    __bf16* kt2 = (__bf16*)smem + 4608;            // [9216, 26624) B : 64 x 136 bf16
    const int lane = threadIdx.x & 63;
    const int wave = threadIdx.x >> 6;
    const int q = lane >> 4, t = lane & 15;
    const int base = blockIdx.x * 64;

    const int eg = base + lane;
    const int egc = eg < NE ? eg : NE - 1;
    const bool wvalid = eg < NE;
    const int pos = pos_r[egc];

    // ---- early: gather h[col] + first B-frags (latency hidden by phases 1-2) ----
    int col = eidx[NE + egc];
    float hcol[32];
    {
        const f32x4* hp = (const f32x4*)(h + (size_t)col * 32);
        #pragma unroll
        for (int v = 0; v < 8; ++v) {
            f32x4 hv = hp[v];
            hcol[v*4+0] = hv.x; hcol[v*4+1] = hv.y; hcol[v*4+2] = hv.z; hcol[v*4+3] = hv.w;
        }
    }
    bf16x8 bcur[8];
    {
        const __bf16* wb0 = w3sw + (size_t)(wave * 8) * 4096;
        #pragma unroll
        for (int f = 0; f < 8; ++f)
            bcur[f] = *(const bf16x8*)(wb0 + (f*64 + lane) * 8);
    }

    // ---- phase 1: layer1, wave-split channels (each wave: 16 ch of 64 edges) ----
    {
        int r = eidx[egc];
        float dx = coord[r*3+0] - coord[col*3+0];
        float dy = coord[r*3+1] - coord[col*3+1];
        float dz = coord[r*3+2] - coord[col*3+2];
        float rad = dx*dx + dy*dy + dz*dz;
        if (wave == 0 && wvalid) {
            f32x4 cdv = {dx, dy, dz, rad};
            *(f32x4*)(cds + (size_t)pos*4) = cdv;
        }
        float kin[7];
        #pragma unroll
        for (int a = 0; a < 6; ++a) kin[a] = eattr[(size_t)egc*6 + a];
        kin[6] = rad;

        const int g0 = wave * 16;
        f32x4 acc1[4];
        #pragma unroll
        for (int g = 0; g < 4; ++g) acc1[g] = *(const f32x4*)(b1 + g0 + g*4);
        #pragma unroll
        for (int t7 = 0; t7 < 7; ++t7) {
            float kv = kin[t7];
            #pragma unroll
            for (int g = 0; g < 4; ++g)
                acc1[g] += kv * (*(const f32x4*)(w1 + t7*64 + g0 + g*4));
        }
        #pragma unroll
        for (int cc = 0; cc < 2; ++cc) {
            f32x4 a0 = relu4(acc1[cc*2]), a1 = relu4(acc1[cc*2+1]);
            bf16x8 pk = {(__bf16)a0.x, (__bf16)a0.y, (__bf16)a0.z, (__bf16)a0.w,
                         (__bf16)a1.x, (__bf16)a1.y, (__bf16)a1.z, (__bf16)a1.w};
            int chunk = wave*2 + cc;
            *(bf16x8*)(kt1 + lane*72 + ((chunk ^ (lane & 7)) * 8)) = pk;
        }
    }
    __syncthreads();                               // k1 complete

    // ---- phase 2: layer2 MFMA (wave handles nt = 2*wave, 2*wave+1) ----
    {
        bf16x8 af[4][2];
        #pragma unroll
        for (int mt = 0; mt < 4; ++mt) {
            int ep = mt*16 + t;
            #pragma unroll
            for (int ks = 0; ks < 2; ++ks)
                af[mt][ks] = *(const bf16x8*)(kt1 + ep*72 + (((ks*4 + q) ^ (ep & 7)) * 8));
        }
        #pragma unroll
        for (int nn = 0; nn < 2; ++nn) {
            int nt = wave*2 + nn;
            f32x4 a2[4];
            #pragma unroll
            for (int mt = 0; mt < 4; ++mt) a2[mt] = (f32x4){0.f, 0.f, 0.f, 0.f};
            #pragma unroll
            for (int ks = 0; ks < 2; ++ks) {
                bf16x8 bf_ = *(const bf16x8*)(w2sw + ((nt*2 + ks)*64 + lane) * 8);
                #pragma unroll
                for (int mt = 0; mt < 4; ++mt)
                    a2[mt] = __builtin_amdgcn_mfma_f32_16x16x32_bf16(af[mt][ks], bf_, a2[mt], 0, 0, 0);
            }
            float bias = b2[nt*16 + t];
            int chunk = nt*2 + (t >> 3);
            int tin = t & 7;
            #pragma unroll
            for (int mt = 0; mt < 4; ++mt) {
                #pragma unroll
                for (int rr = 0; rr < 4; ++rr) {
                    int row = mt*16 + q*4 + rr;
                    kt2[row*136 + ((chunk ^ (row & 15)) * 8) + tin] =
                        (__bf16)fmaxf(a2[mt][rr] + bias, 0.f);
                }
            }
        }
    }
    __syncthreads();                               // k2 complete

    // ---- main A-frags from k2 tile ----
    bf16x8 afrag[4][4];
    #pragma unroll
    for (int mt = 0; mt < 4; ++mt) {
        int ep = mt*16 + t;
        #pragma unroll
        for (int ks = 0; ks < 4; ++ks) {
            int ck = ks*4 + q;
            afrag[mt][ks] = *(const bf16x8*)(kt2 + ep*136 + ((ck ^ (ep & 15)) * 8));
        }
    }
    __syncthreads();                               // afrag loaded; wk may clobber

    // ---- phase 3: big GEMM i-loop ----
    float* wkw = smem + wave * (64 * 36);
    const float* wkrow = wkw + lane * 36;
    float mv[8];

    #pragma unroll
    for (int ii = 0; ii < 8; ++ii) {
        const int i = wave * 8 + ii;
        f32x4 acc[4][2];
        #pragma unroll
        for (int mt = 0; mt < 4; ++mt) {
            acc[mt][0] = (f32x4){0.f, 0.f, 0.f, 0.f};
            acc[mt][1] = (f32x4){0.f, 0.f, 0.f, 0.f};
        }
        #pragma unroll
        for (int jt = 0; jt < 2; ++jt) {
            #pragma unroll
            for (int ks = 0; ks < 4; ++ks) {
                bf16x8 bfrag = bcur[jt*4 + ks];
                #pragma unroll
                for (int mt = 0; mt < 4; ++mt)
                    acc[mt][jt] = __builtin_amdgcn_mfma_f32_16x16x32_bf16(
                        afrag[mt][ks], bfrag, acc[mt][jt], 0, 0, 0);
            }
        }
        if (ii < 7) {
            const __bf16* wbn = w3sw + (size_t)(i + 1) * 4096;
            #pragma unroll
            for (int f = 0; f < 8; ++f)
                bcur[f] = *(const bf16x8*)(wbn + (f*64 + lane) * 8);
        }
        float bias0 = b3[i*32 + t];
        float bias1 = b3[i*32 + 16 + t];
        #pragma unroll
        for (int mt = 0; mt < 4; ++mt) {
            #pragma unroll
            for (int r = 0; r < 4; ++r) {
                int row = mt*16 + q*4 + r;
                wkw[row*36 + t]      = acc[mt][0][r] + bias0;
                wkw[row*36 + 16 + t] = acc[mt][1][r] + bias1;
            }
        }
        float s = 0.f;
        #pragma unroll
        for (int v = 0; v < 8; ++v) {
            f32x4 wv = *(const f32x4*)(wkrow + v*4);
            s += wv.x*hcol[v*4+0] + wv.y*hcol[v*4+1] + wv.z*hcol[v*4+2] + wv.w*hcol[v*4+3];
        }
        mv[ii] = s;
    }

    // store m at row-sorted slot
    if (wvalid) {
        f32x4 v0 = {mv[0], mv[1], mv[2], mv[3]};
        f32x4 v1 = {mv[4], mv[5], mv[6], mv[7]};
        *(f32x4*)(m_s + (size_t)pos*32 + wave*8)     = v0;
        *(f32x4*)(m_s + (size_t)pos*32 + wave*8 + 4) = v1;
    }

    __syncthreads();
    float* mvx = smem;                             // 32 x 65 floats
    #pragma unroll
    for (int ii = 0; ii < 8; ++ii)
        mvx[(wave*8 + ii)*65 + lane] = mv[ii];
    __syncthreads();
    if (wave == 0) {
        float m2[32];
        #pragma unroll
        for (int i = 0; i < 32; ++i) m2[i] = mvx[i*65 + lane];
        float phi = 0.f;
        for (int o = 0; o < 32; o += 4) {
            f32x4 a = *(const f32x4*)(cm_b1 + o);
            #pragma unroll
            for (int i = 0; i < 32; ++i)
                a += m2[i] * (*(const f32x4*)(cm_w1 + i*32 + o));
            a = relu4(a);
            f32x4 w2 = *(const f32x4*)(cm_w2 + o);
            phi += a.x*w2.x + a.y*w2.y + a.z*w2.z + a.w*w2.w;
        }
        if (wvalid) phis[pos] = phi;
    }
}

// CSR gather over SORTED buffers: fully contiguous streaming reads, no
// indirection. 8 threads/node; 2-deep unrolled independent accumulators.
__global__ __launch_bounds__(256, 4)
void k_gather(const int* __restrict__ rowptr,
              const float* __restrict__ m_s, const float* __restrict__ phis,
              const float* __restrict__ cds, const float* __restrict__ deg_inv,
              float* __restrict__ coord, float* __restrict__ h) {
    int tid = blockIdx.x * blockDim.x + threadIdx.x;
    int n = tid >> 3, sub = tid & 7;
    if (n >= NN) return;
    int st = rowptr[n], en = rowptr[n+1];
    f32x4 am0 = {0.f, 0.f, 0.f, 0.f}, am1 = {0.f, 0.f, 0.f, 0.f};
    int p = st;
    for (; p + 1 < en; p += 2) {
        am0 += *(const f32x4*)(m_s + (size_t)p*32 + sub*4);
        am1 += *(const f32x4*)(m_s + (size_t)(p+1)*32 + sub*4);
    }
    if (p < en) am0 += *(const f32x4*)(m_s + (size_t)p*32 + sub*4);
    f32x4 am = am0 + am1;

    float di = deg_inv[n];
    f32x4 hv = *(const f32x4*)(h + (size_t)n*32 + sub*4);
    hv = relu4(hv + am * di);
    *(f32x4*)(h + (size_t)n*32 + sub*4) = hv;

    if (sub == 0) {
        float cx0 = 0.f, cy0 = 0.f, cz0 = 0.f;
        float cx1 = 0.f, cy1 = 0.f, cz1 = 0.f;
        int pp = st;
        for (; pp + 1 < en; pp += 2) {
            f32x4 cd0 = *(const f32x4*)(cds + (size_t)pp*4);
            f32x4 cd1 = *(const f32x4*)(cds + (size_t)(pp+1)*4);
            float p0 = phis[pp], p1 = phis[pp+1];
            cx0 += cd0.x * p0; cy0 += cd0.y * p0; cz0 += cd0.z * p0;
            cx1 += cd1.x * p1; cy1 += cd1.y * p1; cz1 += cd1.z * p1;
        }
        if (pp < en) {
            f32x4 cd0 = *(const f32x4*)(cds + (size_t)pp*4);
            float p0 = phis[pp];
            cx0 += cd0.x * p0; cy0 += cd0.y * p0; cz0 += cd0.z * p0;
        }
        coord[n*3+0] += (cx0 + cx1) * di;
        coord[n*3+1] += (cy0 + cy1) * di;
        coord[n*3+2] += (cz0 + cz1) * di;
    }
}

__global__ __launch_bounds__(256, 4)
void k_final(const float* __restrict__ h, const float* __restrict__ coord,
             const float* __restrict__ fw1, const float* __restrict__ fb1,
             const float* __restrict__ fw2, const float* __restrict__ fb2,
             float* __restrict__ out) {
    int n = blockIdx.x * blockDim.x + threadIdx.x;
    if (n >= NN) return;
    float hreg[32];
    #pragma unroll
    for (int i = 0; i < 32; ++i) hreg[i] = h[n*32 + i];
    float ov = fb2[0];
    for (int o = 0; o < 64; o += 4) {
        f32x4 a = *(const f32x4*)(fb1 + o);
        #pragma unroll
        for (int i = 0; i < 32; ++i)
            a += hreg[i] * (*(const f32x4*)(fw1 + i*64 + o));
        a = relu4(a);
        f32x4 w2 = *(const f32x4*)(fw2 + o);
        ov += a.x*w2.x + a.y*w2.y + a.z*w2.z + a.w*w2.w;
    }
    out[n] = ov;
    out[NN + n*3 + 0] = coord[n*3+0];
    out[NN + n*3 + 1] = coord[n*3+1];
    out[NN + n*3 + 2] = coord[n*3+2];
}

// ---------------- launch ----------------

extern "C" void kernel_launch(void* const* d_in, const int* in_sizes, int n_in,
                              void* d_out, int out_size, void* d_ws, size_t ws_size,
                              hipStream_t stream) {
    const float* x      = (const float*)d_in[0];
    const int*   eidx   = (const int*)  d_in[1];
    const float* eattr  = (const float*)d_in[2];
    const float* cinit  = (const float*)d_in[3];
    const float* fc1w   = (const float*)d_in[4];
    const float* fc1b   = (const float*)d_in[5];
    const float* kw1    = (const float*)d_in[6];
    const float* kb1    = (const float*)d_in[7];
    const float* kw2    = (const float*)d_in[8];
    const float* kb2    = (const float*)d_in[9];
    const float* kw3    = (const float*)d_in[10];
    const float* kb3    = (const float*)d_in[11];
    const float* cmw1   = (const float*)d_in[12];
    const float* cmb1   = (const float*)d_in[13];
    const float* cmw2   = (const float*)d_in[14];
    const float* f2w1   = (const float*)d_in[15];
    const float* f2b1   = (const float*)d_in[16];
    const float* f2w2   = (const float*)d_in[17];
    const float* f2b2   = (const float*)d_in[18];
    float* out = (float*)d_out;

    char* p = (char*)d_ws;
    auto carve = [&](size_t bytes) {
        void* r = (void*)p;
        p += (bytes + 255) & ~(size_t)255;
        return r;
    };
    float*  h        = (float*) carve((size_t)NN * 32 * 4);
    float*  coord    = (float*) carve((size_t)NN * 3 * 4);
    int*    deg      = (int*)   carve((size_t)NN * 4);
    float*  deg_inv  = (float*) carve((size_t)NN * 4);
    int*    rowptr   = (int*)   carve((size_t)(NN + 1) * 4);
    int*    cursor   = (int*)   carve((size_t)NN * 4);
    int*    ebyrow   = (int*)   carve((size_t)NE * 4);
    int*    pos_r    = (int*)   carve((size_t)NE * 4);
    float*  cds      = (float*) carve((size_t)NE * 4 * 4);
    float*  m_s      = (float*) carve((size_t)NE * 32 * 4);
    float*  phis     = (float*) carve((size_t)NE * 4);
    __bf16* w3sw     = (__bf16*)carve((size_t)131072 * 2);
    __bf16* w2sw     = (__bf16*)carve((size_t)8192 * 2);

    const int TB = 256;
    dim3 gE((NE + TB - 1) / TB), gN((NN + TB - 1) / TB), b(TB);
    dim3 gG((NE + 63) / 64);
    dim3 gA((NN*8 + TB - 1) / TB);

    hipMemsetAsync(deg, 0, (size_t)NN * 4, stream);
    k_deg <<<gE, b, 0, stream>>>(eidx, deg);
    k_scan<<<1, b, 0, stream>>>(deg, rowptr, cursor);
    k_fill<<<gE, b, 0, stream>>>(eidx, cursor, ebyrow, pos_r);
    k_init<<<gN, b, 0, stream>>>(x, fc1w, fc1b, cinit, deg, h, coord, deg_inv);
    k_wsw <<<544, b, 0, stream>>>(kw3, w3sw, kw2, w2sw);

    for (int d = 0; d < 3; ++d) {
        k_layer<<<gG, b, 0, stream>>>(coord, eidx, eattr, kw1, kb1, w2sw, kb2,
                                      w3sw, kb3, h, cmw1, cmb1, cmw2, pos_r,
                                      cds, m_s, phis);
        k_gather<<<gA, b, 0, stream>>>(rowptr, m_s, phis, cds, deg_inv, coord, h);
    }
    k_final<<<gN, b, 0, stream>>>(h, coord, f2w1, f2b1, f2w2, f2b2, out);
}

// Round 13
// 359.156 us; speedup vs baseline: 1.1495x; 1.1086x over previous
//
#include <hip/hip_runtime.h>
#include <hip/hip_bf16.h>

#define NN 10000
#define NE 100000

typedef __bf16 bf16x8 __attribute__((ext_vector_type(8)));
typedef float  f32x4  __attribute__((ext_vector_type(4)));

__device__ __forceinline__ f32x4 relu4(f32x4 a) {
    a.x = fmaxf(a.x, 0.f); a.y = fmaxf(a.y, 0.f);
    a.z = fmaxf(a.z, 0.f); a.w = fmaxf(a.w, 0.f);
    return a;
}

// ---------------- one-time kernels ----------------

__global__ void k_deg(const int* __restrict__ eidx, int* __restrict__ deg) {
    int e = blockIdx.x * blockDim.x + threadIdx.x;
    if (e < NE) atomicAdd(&deg[eidx[e]], 1);
}

// Exclusive scan + deg_inv.
__global__ void k_scan(const int* __restrict__ deg, int* __restrict__ rowptr,
                       int* __restrict__ cursor, float* __restrict__ deg_inv) {
    __shared__ int ssum[256];
    const int tid = threadIdx.x;
    const int CH = 40;
    const int base = tid * CH;
    int s = 0;
    for (int i = 0; i < CH; ++i) { int n = base + i; if (n < NN) s += deg[n]; }
    ssum[tid] = s;
    __syncthreads();
    for (int off = 1; off < 256; off <<= 1) {
        int t = (tid >= off) ? ssum[tid - off] : 0;
        __syncthreads();
        ssum[tid] += t;
        __syncthreads();
    }
    int run = ssum[tid] - s;
    for (int i = 0; i < CH; ++i) {
        int n = base + i;
        if (n < NN) {
            int d = deg[n];
            rowptr[n] = run; cursor[n] = run; run += d;
            deg_inv[n] = 1.0f / (float)(d > 1 ? d : 1);
        }
    }
    if (tid == 255) rowptr[NN] = ssum[255];
}

__global__ void k_fill(const int* __restrict__ eidx, int* __restrict__ cursor,
                       int* __restrict__ ebyrow, int* __restrict__ pos_r) {
    int e = blockIdx.x * blockDim.x + threadIdx.x;
    if (e < NE) {
        int r = eidx[e];
        int slot = atomicAdd(&cursor[r], 1);
        ebyrow[slot] = e;
        pos_r[e] = slot;
    }
}

// Merged: w3/w2 swizzles + h/coord init (range-split grid).
__global__ void k_setup(const float* __restrict__ w3, __bf16* __restrict__ w3sw,
                        const float* __restrict__ w2, __bf16* __restrict__ w2sw,
                        const float* __restrict__ x, const float* __restrict__ fc1w,
                        const float* __restrict__ fc1b, const float* __restrict__ cinit,
                        float* __restrict__ h, float* __restrict__ coord) {
    int t = blockIdx.x * blockDim.x + threadIdx.x;
    if (t < 131072) {
        int jj = t & 7;
        int L  = (t >> 3) & 63;
        int ks = (t >> 9) & 3;
        int jt = (t >> 11) & 1;
        int i  = t >> 12;
        int c    = ks*32 + (L >> 4)*8 + jj;              // K index 0..127
        int colv = i*32 + jt*16 + (L & 15);              // output col 0..1023
        w3sw[t] = (__bf16)w3[c*1024 + colv];
    } else if (t < 139264) {
        int u = t - 131072;
        int jj = u & 7;
        int L  = (u >> 3) & 63;
        int ks = (u >> 9) & 1;
        int nt = u >> 10;
        int c1 = ks*32 + (L >> 4)*8 + jj;
        int c2 = nt*16 + (L & 15);
        w2sw[u] = (__bf16)w2[c1*128 + c2];
    } else if (t < 139264 + NN) {
        int n = t - 139264;
        float x0 = x[n*3+0], x1 = x[n*3+1], x2 = x[n*3+2];
        #pragma unroll
        for (int j = 0; j < 32; j += 4) {
            f32x4 a = *(const f32x4*)(fc1b + j);
            a += x0 * (*(const f32x4*)(fc1w + 0*32 + j));
            a += x1 * (*(const f32x4*)(fc1w + 1*32 + j));
            a += x2 * (*(const f32x4*)(fc1w + 2*32 + j));
            *(f32x4*)(h + n*32 + j) = a;   // no relu on fc1 (matches reference)
        }
        coord[n*3+0] = cinit[n*3+0];
        coord[n*3+1] = cinit[n*3+1];
        coord[n*3+2] = cinit[n*3+2];
    }
}

// ---------------- the fused per-layer kernel ----------------
// kt2 row stride 128 bf16 (measured: 750k conflicts vs 2.55M at stride 136).
__global__ __launch_bounds__(256, 2)
void k_layer(const float* __restrict__ coord, const int* __restrict__ eidx,
             const float* __restrict__ eattr,
             const float* __restrict__ w1, const float* __restrict__ b1,
             const __bf16* __restrict__ w2sw, const float* __restrict__ b2,
             const __bf16* __restrict__ w3sw, const float* __restrict__ b3,
             const float* __restrict__ h,
             const float* __restrict__ cm_w1, const float* __restrict__ cm_b1,
             const float* __restrict__ cm_w2, const int* __restrict__ pos_r,
             float* __restrict__ cds, float* __restrict__ m_s,
             float* __restrict__ phis) {
    __shared__ float smem[4 * 64 * 36];            // 36.9 KB
    __bf16* kt1 = (__bf16*)smem;                   // [0, 9216) B : 64 x 72 bf16
    __bf16* kt2 = (__bf16*)smem + 4608;            // [9216, 25600) B : 64 x 128 bf16
    const int lane = threadIdx.x & 63;
    const int wave = threadIdx.x >> 6;
    const int q = lane >> 4, t = lane & 15;
    const int base = blockIdx.x * 64;

    const int eg = base + lane;
    const int egc = eg < NE ? eg : NE - 1;
    const bool wvalid = eg < NE;
    const int pos = pos_r[egc];

    // early: gather h[col] + first B-frags (latency hidden by phases 1-2)
    int col = eidx[NE + egc];
    float hcol[32];
    {
        const f32x4* hp = (const f32x4*)(h + (size_t)col * 32);
        #pragma unroll
        for (int v = 0; v < 8; ++v) {
            f32x4 hv = hp[v];
            hcol[v*4+0] = hv.x; hcol[v*4+1] = hv.y; hcol[v*4+2] = hv.z; hcol[v*4+3] = hv.w;
        }
    }
    bf16x8 bcur[8];
    {
        const __bf16* wb0 = w3sw + (size_t)(wave * 8) * 4096;
        #pragma unroll
        for (int f = 0; f < 8; ++f)
            bcur[f] = *(const bf16x8*)(wb0 + (f*64 + lane) * 8);
    }

    // ---- phase 1: layer1, wave-split channels ----
    {
        int r = eidx[egc];
        float dx = coord[r*3+0] - coord[col*3+0];
        float dy = coord[r*3+1] - coord[col*3+1];
        float dz = coord[r*3+2] - coord[col*3+2];
        float rad = dx*dx + dy*dy + dz*dz;
        if (wave == 0 && wvalid) {
            f32x4 cdv = {dx, dy, dz, rad};
            *(f32x4*)(cds + (size_t)pos*4) = cdv;
        }
        float kin[7];
        #pragma unroll
        for (int a = 0; a < 6; ++a) kin[a] = eattr[(size_t)egc*6 + a];
        kin[6] = rad;

        const int g0 = wave * 16;
        f32x4 acc1[4];
        #pragma unroll
        for (int g = 0; g < 4; ++g) acc1[g] = *(const f32x4*)(b1 + g0 + g*4);
        #pragma unroll
        for (int t7 = 0; t7 < 7; ++t7) {
            float kv = kin[t7];
            #pragma unroll
            for (int g = 0; g < 4; ++g)
                acc1[g] += kv * (*(const f32x4*)(w1 + t7*64 + g0 + g*4));
        }
        #pragma unroll
        for (int cc = 0; cc < 2; ++cc) {
            f32x4 a0 = relu4(acc1[cc*2]), a1 = relu4(acc1[cc*2+1]);
            bf16x8 pk = {(__bf16)a0.x, (__bf16)a0.y, (__bf16)a0.z, (__bf16)a0.w,
                         (__bf16)a1.x, (__bf16)a1.y, (__bf16)a1.z, (__bf16)a1.w};
            int chunk = wave*2 + cc;
            *(bf16x8*)(kt1 + lane*72 + ((chunk ^ (lane & 7)) * 8)) = pk;
        }
    }
    __syncthreads();                               // k1 complete

    // ---- phase 2: layer2 MFMA (wave handles nt = 2*wave, 2*wave+1) ----
    {
        bf16x8 af[4][2];
        #pragma unroll
        for (int mt = 0; mt < 4; ++mt) {
            int ep = mt*16 + t;
            #pragma unroll
            for (int ks = 0; ks < 2; ++ks)
                af[mt][ks] = *(const bf16x8*)(kt1 + ep*72 + (((ks*4 + q) ^ (ep & 7)) * 8));
        }
        #pragma unroll
        for (int nn = 0; nn < 2; ++nn) {
            int nt = wave*2 + nn;
            f32x4 a2[4];
            #pragma unroll
            for (int mt = 0; mt < 4; ++mt) a2[mt] = (f32x4){0.f, 0.f, 0.f, 0.f};
            #pragma unroll
            for (int ks = 0; ks < 2; ++ks) {
                bf16x8 bf_ = *(const bf16x8*)(w2sw + ((nt*2 + ks)*64 + lane) * 8);
                #pragma unroll
                for (int mt = 0; mt < 4; ++mt)
                    a2[mt] = __builtin_amdgcn_mfma_f32_16x16x32_bf16(af[mt][ks], bf_, a2[mt], 0, 0, 0);
            }
            float bias = b2[nt*16 + t];
            int chunk = nt*2 + (t >> 3);
            int tin = t & 7;
            #pragma unroll
            for (int mt = 0; mt < 4; ++mt) {
                #pragma unroll
                for (int rr = 0; rr < 4; ++rr) {
                    int row = mt*16 + q*4 + rr;
                    kt2[row*128 + ((chunk ^ (row & 15)) * 8) + tin] =
                        (__bf16)fmaxf(a2[mt][rr] + bias, 0.f);
                }
            }
        }
    }
    __syncthreads();                               // k2 complete

    // ---- main A-frags from k2 tile ----
    bf16x8 afrag[4][4];
    #pragma unroll
    for (int mt = 0; mt < 4; ++mt) {
        int ep = mt*16 + t;
        #pragma unroll
        for (int ks = 0; ks < 4; ++ks) {
            int ck = ks*4 + q;
            afrag[mt][ks] = *(const bf16x8*)(kt2 + ep*128 + ((ck ^ (ep & 15)) * 8));
        }
    }
    __syncthreads();                               // afrag loaded; wk may clobber

    // ---- phase 3: big GEMM i-loop ----
    float* wkw = smem + wave * (64 * 36);
    const float* wkrow = wkw + lane * 36;
    float mv[8];

    #pragma unroll
    for (int ii = 0; ii < 8; ++ii) {
        const int i = wave * 8 + ii;
        f32x4 acc[4][2];
        #pragma unroll
        for (int mt = 0; mt < 4; ++mt) {
            acc[mt][0] = (f32x4){0.f, 0.f, 0.f, 0.f};
            acc[mt][1] = (f32x4){0.f, 0.f, 0.f, 0.f};
        }
        #pragma unroll
        for (int jt = 0; jt < 2; ++jt) {
            #pragma unroll
            for (int ks = 0; ks < 4; ++ks) {
                bf16x8 bfrag = bcur[jt*4 + ks];
                #pragma unroll
                for (int mt = 0; mt < 4; ++mt)
                    acc[mt][jt] = __builtin_amdgcn_mfma_f32_16x16x32_bf16(
                        afrag[mt][ks], bfrag, acc[mt][jt], 0, 0, 0);
            }
        }
        if (ii < 7) {
            const __bf16* wbn = w3sw + (size_t)(i + 1) * 4096;
            #pragma unroll
            for (int f = 0; f < 8; ++f)
                bcur[f] = *(const bf16x8*)(wbn + (f*64 + lane) * 8);
        }
        float bias0 = b3[i*32 + t];
        float bias1 = b3[i*32 + 16 + t];
        #pragma unroll
        for (int mt = 0; mt < 4; ++mt) {
            #pragma unroll
            for (int r = 0; r < 4; ++r) {
                int row = mt*16 + q*4 + r;
                wkw[row*36 + t]      = acc[mt][0][r] + bias0;
                wkw[row*36 + 16 + t] = acc[mt][1][r] + bias1;
            }
        }
        float s = 0.f;
        #pragma unroll
        for (int v = 0; v < 8; ++v) {
            f32x4 wv = *(const f32x4*)(wkrow + v*4);
            s += wv.x*hcol[v*4+0] + wv.y*hcol[v*4+1] + wv.z*hcol[v*4+2] + wv.w*hcol[v*4+3];
        }
        mv[ii] = s;
    }

    if (wvalid) {
        f32x4 v0 = {mv[0], mv[1], mv[2], mv[3]};
        f32x4 v1 = {mv[4], mv[5], mv[6], mv[7]};
        *(f32x4*)(m_s + (size_t)pos*32 + wave*8)     = v0;
        *(f32x4*)(m_s + (size_t)pos*32 + wave*8 + 4) = v1;
    }

    __syncthreads();
    float* mvx = smem;                             // 32 x 65 floats
    #pragma unroll
    for (int ii = 0; ii < 8; ++ii)
        mvx[(wave*8 + ii)*65 + lane] = mv[ii];
    __syncthreads();
    if (wave == 0) {
        float m2[32];
        #pragma unroll
        for (int i = 0; i < 32; ++i) m2[i] = mvx[i*65 + lane];
        float phi = 0.f;
        for (int o = 0; o < 32; o += 4) {
            f32x4 a = *(const f32x4*)(cm_b1 + o);
            #pragma unroll
            for (int i = 0; i < 32; ++i)
                a += m2[i] * (*(const f32x4*)(cm_w1 + i*32 + o));
            a = relu4(a);
            f32x4 w2 = *(const f32x4*)(cm_w2 + o);
            phi += a.x*w2.x + a.y*w2.y + a.z*w2.z + a.w*w2.w;
        }
        if (wvalid) phis[pos] = phi;
    }
}

// CSR gather over SORTED buffers (contiguous streams). 8 threads/node.
// dofinal: fuse the output MLP (h kept in regs, exchanged via intra-group shfl).
__global__ __launch_bounds__(256, 4)
void k_gather(const int* __restrict__ rowptr,
              const float* __restrict__ m_s, const float* __restrict__ phis,
              const float* __restrict__ cds, const float* __restrict__ deg_inv,
              float* __restrict__ coord, float* __restrict__ h,
              const float* __restrict__ fw1, const float* __restrict__ fb1,
              const float* __restrict__ fw2, const float* __restrict__ fb2,
              float* __restrict__ out, int dofinal) {
    int tid = blockIdx.x * blockDim.x + threadIdx.x;
    int n = tid >> 3, sub = tid & 7;
    if (n >= NN) return;
    int st = rowptr[n], en = rowptr[n+1];
    f32x4 am0 = {0.f, 0.f, 0.f, 0.f}, am1 = {0.f, 0.f, 0.f, 0.f};
    int p = st;
    for (; p + 1 < en; p += 2) {
        am0 += *(const f32x4*)(m_s + (size_t)p*32 + sub*4);
        am1 += *(const f32x4*)(m_s + (size_t)(p+1)*32 + sub*4);
    }
    if (p < en) am0 += *(const f32x4*)(m_s + (size_t)p*32 + sub*4);
    f32x4 am = am0 + am1;

    float di = deg_inv[n];
    f32x4 hv = *(const f32x4*)(h + (size_t)n*32 + sub*4);
    hv = relu4(hv + am * di);

    // coord update (sub 0 only)
    float c0 = 0.f, c1 = 0.f, c2 = 0.f;
    if (sub == 0) {
        float cx0 = 0.f, cy0 = 0.f, cz0 = 0.f;
        float cx1 = 0.f, cy1 = 0.f, cz1 = 0.f;
        int pp = st;
        for (; pp + 1 < en; pp += 2) {
            f32x4 cd0 = *(const f32x4*)(cds + (size_t)pp*4);
            f32x4 cd1 = *(const f32x4*)(cds + (size_t)(pp+1)*4);
            float p0 = phis[pp], p1 = phis[pp+1];
            cx0 += cd0.x * p0; cy0 += cd0.y * p0; cz0 += cd0.z * p0;
            cx1 += cd1.x * p1; cy1 += cd1.y * p1; cz1 += cd1.z * p1;
        }
        if (pp < en) {
            f32x4 cd0 = *(const f32x4*)(cds + (size_t)pp*4);
            float p0 = phis[pp];
            cx0 += cd0.x * p0; cy0 += cd0.y * p0; cz0 += cd0.z * p0;
        }
        c0 = coord[n*3+0] + (cx0 + cx1) * di;
        c1 = coord[n*3+1] + (cy0 + cy1) * di;
        c2 = coord[n*3+2] + (cz0 + cz1) * di;
    }

    if (!dofinal) {
        *(f32x4*)(h + (size_t)n*32 + sub*4) = hv;
        if (sub == 0) {
            coord[n*3+0] = c0; coord[n*3+1] = c1; coord[n*3+2] = c2;
        }
        return;
    }

    // ---- fused final MLP: collect h[0..31] via intra-group shfl ----
    const int gbase = (tid & 63) & 56;             // group leader lane
    float hreg[32];
    #pragma unroll
    for (int s2 = 0; s2 < 8; ++s2) {
        hreg[s2*4+0] = __shfl(hv.x, gbase + s2, 64);
        hreg[s2*4+1] = __shfl(hv.y, gbase + s2, 64);
        hreg[s2*4+2] = __shfl(hv.z, gbase + s2, 64);
        hreg[s2*4+3] = __shfl(hv.w, gbase + s2, 64);
    }
    // each lane: 8 hidden units o = sub*8..sub*8+7
    float po = 0.f;
    #pragma unroll
    for (int oo = 0; oo < 8; oo += 4) {
        int o = sub*8 + oo;
        f32x4 a = *(const f32x4*)(fb1 + o);
        #pragma unroll
        for (int i = 0; i < 32; ++i)
            a += hreg[i] * (*(const f32x4*)(fw1 + i*64 + o));
        a = relu4(a);
        f32x4 w2 = *(const f32x4*)(fw2 + o);
        po += a.x*w2.x + a.y*w2.y + a.z*w2.z + a.w*w2.w;
    }
    po += __shfl_xor(po, 1, 64);
    po += __shfl_xor(po, 2, 64);
    po += __shfl_xor(po, 4, 64);
    if (sub == 0) {
        out[n] = po + fb2[0];
        out[NN + n*3 + 0] = c0;
        out[NN + n*3 + 1] = c1;
        out[NN + n*3 + 2] = c2;
    }
}

// ---------------- launch ----------------

extern "C" void kernel_launch(void* const* d_in, const int* in_sizes, int n_in,
                              void* d_out, int out_size, void* d_ws, size_t ws_size,
                              hipStream_t stream) {
    const float* x      = (const float*)d_in[0];
    const int*   eidx   = (const int*)  d_in[1];
    const float* eattr  = (const float*)d_in[2];
    const float* cinit  = (const float*)d_in[3];
    const float* fc1w   = (const float*)d_in[4];
    const float* fc1b   = (const float*)d_in[5];
    const float* kw1    = (const float*)d_in[6];
    const float* kb1    = (const float*)d_in[7];
    const float* kw2    = (const float*)d_in[8];
    const float* kb2    = (const float*)d_in[9];
    const float* kw3    = (const float*)d_in[10];
    const float* kb3    = (const float*)d_in[11];
    const float* cmw1   = (const float*)d_in[12];
    const float* cmb1   = (const float*)d_in[13];
    const float* cmw2   = (const float*)d_in[14];
    const float* f2w1   = (const float*)d_in[15];
    const float* f2b1   = (const float*)d_in[16];
    const float* f2w2   = (const float*)d_in[17];
    const float* f2b2   = (const float*)d_in[18];
    float* out = (float*)d_out;

    char* p = (char*)d_ws;
    auto carve = [&](size_t bytes) {
        void* r = (void*)p;
        p += (bytes + 255) & ~(size_t)255;
        return r;
    };
    float*  h        = (float*) carve((size_t)NN * 32 * 4);
    float*  coord    = (float*) carve((size_t)NN * 3 * 4);
    int*    deg      = (int*)   carve((size_t)NN * 4);
    float*  deg_inv  = (float*) carve((size_t)NN * 4);
    int*    rowptr   = (int*)   carve((size_t)(NN + 1) * 4);
    int*    cursor   = (int*)   carve((size_t)NN * 4);
    int*    ebyrow   = (int*)   carve((size_t)NE * 4);
    int*    pos_r    = (int*)   carve((size_t)NE * 4);
    float*  cds      = (float*) carve((size_t)NE * 4 * 4);
    float*  m_s      = (float*) carve((size_t)NE * 32 * 4);
    float*  phis     = (float*) carve((size_t)NE * 4);
    __bf16* w3sw     = (__bf16*)carve((size_t)131072 * 2);
    __bf16* w2sw     = (__bf16*)carve((size_t)8192 * 2);

    const int TB = 256;
    dim3 gE((NE + TB - 1) / TB), b(TB);
    dim3 gS((139264 + NN + TB - 1) / TB);
    dim3 gG((NE + 63) / 64);
    dim3 gA((NN*8 + TB - 1) / TB);

    hipMemsetAsync(deg, 0, (size_t)NN * 4, stream);
    k_deg  <<<gE, b, 0, stream>>>(eidx, deg);
    k_scan <<<1, b, 0, stream>>>(deg, rowptr, cursor, deg_inv);
    k_fill <<<gE, b, 0, stream>>>(eidx, cursor, ebyrow, pos_r);
    k_setup<<<gS, b, 0, stream>>>(kw3, w3sw, kw2, w2sw, x, fc1w, fc1b, cinit, h, coord);

    for (int d = 0; d < 3; ++d) {
        k_layer<<<gG, b, 0, stream>>>(coord, eidx, eattr, kw1, kb1, w2sw, kb2,
                                      w3sw, kb3, h, cmw1, cmb1, cmw2, pos_r,
                                      cds, m_s, phis);
        k_gather<<<gA, b, 0, stream>>>(rowptr, m_s, phis, cds, deg_inv, coord, h,
                                       f2w1, f2b1, f2w2, f2b2, out, d == 2 ? 1 : 0);
    }
}